// Round 12
// baseline (278.125 us; speedup 1.0000x reference)
//
#include <hip/hip_runtime.h>

// Problem: B=4, N=2048, C=768, H=12, D=64. I/O f32; internals bf16 MFMA + f32 acc.
// Pipeline: prep(LN + W transposes) -> QKV GEMM (Q*0.125*log2e, K; V^T fused) ->
//           flash attention (split-K x2, unnormalized partials) -> combine -> out GEMM.
// R12: (a) attn split-K x2: R11 showed attn grid-capped at 3 blocks/CU (conflicts=0 and
//     FETCH 18MB changed nothing -> latency/occupancy bound). 1536 blocks -> 4/CU
//     resident, 6/CU queued. Partials alias dead ws regions (od0->os, od1->xn,
//     l->wqkvT; combine writes into dead ks region; gemm_out reads it).
//     (b) LN + transposes fused into one prep kernel (2 fewer launch gaps).
//     (c) GEMMs unchanged from R11 (BK=64 plateau accepted).

typedef __bf16 bf16x8 __attribute__((ext_vector_type(8)));
typedef float  f32x4  __attribute__((ext_vector_type(4)));

#define MFMA16(a,b,c) __builtin_amdgcn_mfma_f32_16x16x32_bf16((a),(b),(c),0,0,0)

__device__ inline f32x4 zero4() { f32x4 z = {0.f,0.f,0.f,0.f}; return z; }

// async global->LDS, 16B per lane; lds dest is wave-uniform base + lane*16
__device__ inline void gll16(const __bf16* g, __bf16* l) {
  __builtin_amdgcn_global_load_lds((const __attribute__((address_space(1))) unsigned int*)g,
                                   (__attribute__((address_space(3))) unsigned int*)l,
                                   16, 0, 0);
}

// truncating f32 -> bf16 (round toward zero): no RNE software sequence
__device__ inline __bf16 bf16_trunc(float f) {
  const unsigned int u = __builtin_bit_cast(unsigned int, f);
  return __builtin_bit_cast(__bf16, (unsigned short)(u >> 16));
}

// ---------------- Fused prep: LN rows + wqkv^T + wout^T in one launch ----------------
// blocks [0,8192): LN row; [8192,9920): wqkv^T 32x32 tile; [9920,10496): wout^T tile.
__global__ __launch_bounds__(256) void prep_kernel(const float* __restrict__ x,
                                                   const float* __restrict__ g,
                                                   const float* __restrict__ bt,
                                                   const float* __restrict__ wqkv,
                                                   const float* __restrict__ wout,
                                                   __bf16* __restrict__ xn,
                                                   __bf16* __restrict__ wqkvT,
                                                   __bf16* __restrict__ woutT) {
  __shared__ float t[32][33];
  const int tid = threadIdx.x;
  if (blockIdx.x < 8192) {
    const int row = blockIdx.x;
    const float* xr = x + (size_t)row * 768;
    float v[3]; float s = 0.f, ss = 0.f;
    #pragma unroll
    for (int i = 0; i < 3; ++i) { float f = xr[tid + 256*i]; v[i] = f; s += f; ss += f*f; }
    #pragma unroll
    for (int m = 32; m >= 1; m >>= 1) { s += __shfl_xor(s, m, 64); ss += __shfl_xor(ss, m, 64); }
    float* red = &t[0][0];
    const int wave = tid >> 6;
    if ((tid & 63) == 0) { red[wave] = s; red[4 + wave] = ss; }
    __syncthreads();
    s  = red[0] + red[1] + red[2] + red[3];
    ss = red[4] + red[5] + red[6] + red[7];
    const float mu  = s * (1.f/768.f);
    const float var = ss * (1.f/768.f) - mu*mu;
    const float inv = rsqrtf(var + 1e-5f);
    __bf16* xo = xn + (size_t)row * 768;
    #pragma unroll
    for (int i = 0; i < 3; ++i) {
      const int c0 = tid + 256*i;
      xo[c0] = (__bf16)((v[i] - mu) * inv * g[c0] + bt[c0]);
    }
  } else {
    const float* in; __bf16* out; int R, C, cx, ry;
    if (blockIdx.x < 8192 + 1728) {
      const int i = blockIdx.x - 8192;
      in = wqkv; out = wqkvT; R = 768; C = 2304; cx = i % 72; ry = i / 72;
    } else {
      const int i = blockIdx.x - 8192 - 1728;
      in = wout; out = woutT; R = 768; C = 768; cx = i % 24; ry = i / 24;
    }
    const int tx = tid & 31, ty = tid >> 5;
    const int c0 = cx * 32, r0 = ry * 32;
    #pragma unroll
    for (int p = 0; p < 4; ++p) t[ty + 8*p][tx] = in[(size_t)(r0 + ty + 8*p) * C + c0 + tx];
    __syncthreads();
    #pragma unroll
    for (int p = 0; p < 4; ++p) out[(size_t)(c0 + ty + 8*p) * R + r0 + tx] = (__bf16)t[tx][ty + 8*p];
  }
}

// ---------------- GEMM mainloop BK=64 (R11): C[128x128] = A[M,K] @ BT[N,K]^T ----------------
template<int KDIM>
__device__ inline void gemm_mainloop(const __bf16* __restrict__ A, const __bf16* __restrict__ BT,
                                     int bm, int bn, int wave, int lane,
                                     f32x4 acc[4][4], __bf16* Asm, __bf16* Bsm) {
  const int wm = wave >> 1, wn = wave & 1;
  const int lr = lane & 15, lk = lane >> 4;
  for (int k0 = 0; k0 < KDIM; k0 += 64) {
    #pragma unroll
    for (int s2 = 0; s2 < 4; ++s2) {
      const int st = wave * 4 + s2;
      const int rb = st >> 1, kh = st & 1;
      gll16(A  + (size_t)(bm + rb*16 + lr) * KDIM + k0 + kh*32 + lk*8, Asm + st*512);
      gll16(BT + (size_t)(bn + rb*16 + lr) * KDIM + k0 + kh*32 + lk*8, Bsm + st*512);
    }
    __builtin_amdgcn_s_waitcnt(0);
    __syncthreads();
    #pragma unroll
    for (int ks = 0; ks < 2; ++ks) {
      bf16x8 a[4], b[4];
      #pragma unroll
      for (int mt = 0; mt < 4; ++mt) a[mt] = *(const bf16x8*)(Asm + ((wm*4+mt)*2+ks)*512 + lane*8);
      #pragma unroll
      for (int nt = 0; nt < 4; ++nt) b[nt] = *(const bf16x8*)(Bsm + ((wn*4+nt)*2+ks)*512 + lane*8);
      #pragma unroll
      for (int mt = 0; mt < 4; ++mt)
        #pragma unroll
        for (int nt = 0; nt < 4; ++nt)
          acc[mt][nt] = MFMA16(a[mt], b[nt], acc[mt][nt]);
    }
    __syncthreads();
  }
}

// ---------------- QKV GEMM: xn[8192,768] @ wqkvT[2304,768]^T ----------------
__global__ __launch_bounds__(256) void gemm_qkv_kernel(const __bf16* __restrict__ A,
                                                       const __bf16* __restrict__ BT,
                                                       __bf16* __restrict__ q,
                                                       __bf16* __restrict__ k,
                                                       __bf16* __restrict__ vt) {
  __shared__ __align__(16) __bf16 smem[2*8192];   // Asm+Bsm (32KB); aliased transpose tile
  __bf16* Asm = smem;
  __bf16* Bsm = smem + 8192;
  const int lane = threadIdx.x & 63, wave = threadIdx.x >> 6;
  const int bm = blockIdx.y * 128, bn = blockIdx.x * 128;
  f32x4 acc[4][4];
  #pragma unroll
  for (int i = 0; i < 4; ++i)
    #pragma unroll
    for (int j = 0; j < 4; ++j) acc[i][j] = zero4();
  gemm_mainloop<768>(A, BT, bm, bn, wave, lane, acc, Asm, Bsm);
  const int wm = wave >> 1, wn = wave & 1;
  const int quad = lane >> 4, c = lane & 15;
  if (bn < 1536) {
    const float qscale = 0.125f * 1.44269504088896f;  // 1/sqrt(64) * log2(e)
    #pragma unroll
    for (int mt = 0; mt < 4; ++mt)
      #pragma unroll
      for (int nt = 0; nt < 4; ++nt) {
        const int col = bn + wn*64 + nt*16 + c;           // 0..1535
        const int which = col >= 768 ? 1 : 0;
        const int within = col - which*768;
        const int h = within >> 6, d = within & 63;
        #pragma unroll
        for (int r = 0; r < 4; ++r) {
          const int row = bm + wm*64 + mt*16 + quad*4 + r; // 0..8191
          const int b = row >> 11, n = row & 2047;
          const float vv = acc[mt][nt][r];
          const size_t idx = ((size_t)(b*12 + h) * 2048 + n) * 64 + d;  // [B,H,N,D]
          if (which == 0) q[idx] = (__bf16)(vv * qscale);
          else            k[idx] = (__bf16)vv;
        }
      }
  } else {
    __syncthreads();   // staging buffers dead; reuse as pad-66 transpose tile
    #pragma unroll
    for (int mt = 0; mt < 4; ++mt)
      #pragma unroll
      for (int nt = 0; nt < 4; ++nt) {
        const int lcol = wn*64 + nt*16 + c;
        #pragma unroll
        for (int r = 0; r < 4; ++r) {
          const int lrow = wm*64 + mt*16 + quad*4 + r;
          smem[lrow*66 + lcol] = (__bf16)acc[mt][nt][r];
        }
      }
    __syncthreads();
    const int b = bm >> 11, n0 = bm & 2047;
    const int vo = bn - 1536;
    const int n = threadIdx.x & 127;
    const int csel = threadIdx.x >> 7;
    #pragma unroll
    for (int pass = 0; pass < 64; ++pass) {
      const int lc = pass*2 + csel;
      const int gcol = vo + lc;
      const int h = gcol >> 6, d = gcol & 63;
      vt[((size_t)(b*12 + h)*64 + d)*2048 + n0 + n] = smem[n*66 + lc];
    }
  }
}

// ---------------- Out-proj GEMM: o[8192,768] @ woutT[768,768]^T + f32 bias + f32 residual ----------------
__global__ __launch_bounds__(256) void gemm_out_kernel(const __bf16* __restrict__ A,
                                                       const __bf16* __restrict__ BT,
                                                       const float* __restrict__ bias,
                                                       const float* __restrict__ resid,
                                                       float* __restrict__ out) {
  __shared__ __align__(16) __bf16 Asm[16*512];
  __shared__ __align__(16) __bf16 Bsm[16*512];
  const int lane = threadIdx.x & 63, wave = threadIdx.x >> 6;
  const int bm = blockIdx.y * 128, bn = blockIdx.x * 128;
  f32x4 acc[4][4];
  #pragma unroll
  for (int i = 0; i < 4; ++i)
    #pragma unroll
    for (int j = 0; j < 4; ++j) acc[i][j] = zero4();
  gemm_mainloop<768>(A, BT, bm, bn, wave, lane, acc, Asm, Bsm);
  const int wm = wave >> 1, wn = wave & 1;
  const int quad = lane >> 4, c = lane & 15;
  #pragma unroll
  for (int mt = 0; mt < 4; ++mt)
    #pragma unroll
    for (int nt = 0; nt < 4; ++nt) {
      const int col = bn + wn*64 + nt*16 + c;
      #pragma unroll
      for (int r = 0; r < 4; ++r) {
        const int row = bm + wm*64 + mt*16 + quad*4 + r;
        out[(size_t)row*768 + col] = acc[mt][nt][r] + bias[col] + resid[(size_t)row*768 + col];
      }
    }
}

// ---------------- Flash attention, split-K x2: 1 block = (b,h, key-half) x 128 q-rows ----
// Unnormalized partials: odp[bh][n][d] (bf16) and clp[half][bh][n] (f32) per half.
__global__ __launch_bounds__(256) void attn_kernel(const __bf16* __restrict__ q,
                                                   const __bf16* __restrict__ k,
                                                   const __bf16* __restrict__ vt,
                                                   __bf16* __restrict__ odp0,
                                                   __bf16* __restrict__ odp1,
                                                   float* __restrict__ clp) {
  // XCD swizzle: 1536 blocks = 8 XCDs x 192; 12 (bh,half) groups per XCD so each
  // group's K/V half (256 KB) stays in its 4MB L2.
  const int xcd = blockIdx.x & 7, i = blockIdx.x >> 3;
  const int grp = xcd * 12 + (i >> 4);   // 0..95
  const int qt = i & 15;
  const int bh = grp >> 1, half = grp & 1;
  const int lane = threadIdx.x & 63, wave = threadIdx.x >> 6;
  const int c = lane & 15, quad = lane >> 4;
  const int lr = lane & 15, lk = lane >> 4;
  const int q0 = qt*128 + wave*32;
  const int kbase = half * 1024;

  const __bf16* qb = q  + ((size_t)bh*2048 + q0) * 64;
  const __bf16* kb = k  + (size_t)bh * 2048 * 64;
  const __bf16* vb = vt + (size_t)bh * 64 * 2048;

  __shared__ __align__(16) __bf16 Ksm[2][4096];
  __shared__ __align__(16) __bf16 Vsm[2][4096];
  __shared__ __align__(16) __bf16 plds[4][1024];
  __bf16* myp = plds[wave];

  bf16x8 aq[2][2];
  #pragma unroll
  for (int rg = 0; rg < 2; ++rg) {
    aq[rg][0] = *(const bf16x8*)(qb + (size_t)(rg*16 + c)*64 + quad*8);
    aq[rg][1] = *(const bf16x8*)(qb + (size_t)(rg*16 + c)*64 + 32 + quad*8);
  }

  float cl[2][4];
  f32x4 od[2][4];
  #pragma unroll
  for (int rg = 0; rg < 2; ++rg)
    #pragma unroll
    for (int r = 0; r < 4; ++r) { cl[rg][r] = 0.f; od[rg][r] = zero4(); }

  auto stage = [&](int it) {
    const int kt = kbase + it * 64;
    __bf16* Ks = Ksm[it & 1];
    __bf16* Vs = Vsm[it & 1];
    gll16(kb + (size_t)(kt + wave*16 + lr) * 64 + lk*8,        Ks + (wave*2+0)*512);
    gll16(kb + (size_t)(kt + wave*16 + lr) * 64 + 32 + lk*8,   Ks + (wave*2+1)*512);
    gll16(vb + (size_t)(wave*16 + lr) * 2048 + kt + lk*8,      Vs + (wave*2+0)*512);
    gll16(vb + (size_t)(wave*16 + lr) * 2048 + kt + 32 + lk*8, Vs + (wave*2+1)*512);
  };

  stage(0);
  stage(1);

  const int sl = lane ^ ((lane >> 3) & 7);   // swizzled read block index

  for (int it = 0; it < 16; ++it) {
    const __bf16* Ks = Ksm[it & 1];
    const __bf16* Vs = Vsm[it & 1];
    if (it < 15) asm volatile("s_waitcnt vmcnt(4)" ::: "memory");
    else         asm volatile("s_waitcnt vmcnt(0)" ::: "memory");
    asm volatile("s_barrier" ::: "memory");
    #pragma unroll
    for (int ch = 0; ch < 2; ++ch) {         // 32-key chunks
      f32x4 s0[2], s1[2];
      #pragma unroll
      for (int t2 = 0; t2 < 2; ++t2) {
        const int t = ch*2 + t2;
        const bf16x8 b0 = *(const bf16x8*)(Ks + (t*2+0)*512 + lane*8);
        const bf16x8 b1 = *(const bf16x8*)(Ks + (t*2+1)*512 + lane*8);
        f32x4 z0 = zero4(), z1 = zero4();
        z0 = MFMA16(aq[0][0], b0, z0); z0 = MFMA16(aq[0][1], b1, z0);
        z1 = MFMA16(aq[1][0], b0, z1); z1 = MFMA16(aq[1][1], b1, z1);
        s0[t2] = z0; s1[t2] = z1;
      }
      #pragma unroll
      for (int t2 = 0; t2 < 2; ++t2) {
        const int kk = t2*16 + c;
        const int k8 = kk >> 3, j = kk & 7;
        #pragma unroll
        for (int r = 0; r < 4; ++r) {
          const int row = quad*4 + r;
          const int b = k8*16 + row;
          const int sb = b ^ ((b >> 3) & 7);
          const float p0 = __builtin_amdgcn_exp2f(s0[t2][r]);
          const float p1 = __builtin_amdgcn_exp2f(s1[t2][r]);
          cl[0][r] += p0; cl[1][r] += p1;
          myp[sb*8 + j]       = bf16_trunc(p0);
          myp[512 + sb*8 + j] = bf16_trunc(p1);
        }
      }
      asm volatile("s_waitcnt lgkmcnt(0)" ::: "memory");  // wave-local P write->read
      const bf16x8 ap0 = *(const bf16x8*)(myp + sl*8);
      const bf16x8 ap1 = *(const bf16x8*)(myp + 512 + sl*8);
      asm volatile("" ::: "memory");
      #pragma unroll
      for (int dt = 0; dt < 4; ++dt) {
        const bf16x8 bv = *(const bf16x8*)(Vs + (dt*2+ch)*512 + lane*8);
        od[0][dt] = MFMA16(ap0, bv, od[0][dt]);
        od[1][dt] = MFMA16(ap1, bv, od[1][dt]);
      }
    }
    asm volatile("s_barrier" ::: "memory");
    if (it + 2 < 16) stage(it + 2);
  }
  // store unnormalized partials; cl reduced across the 16 lanes then stored once
  __bf16* odp = half ? odp1 : odp0;
  float* clh = clp + (size_t)(half*48 + bh) * 2048;
  #pragma unroll
  for (int rg = 0; rg < 2; ++rg) {
    float lv[4];
    #pragma unroll
    for (int r = 0; r < 4; ++r) {
      float v0 = cl[rg][r];
      v0 += __shfl_xor(v0, 1); v0 += __shfl_xor(v0, 2);
      v0 += __shfl_xor(v0, 4); v0 += __shfl_xor(v0, 8);
      lv[r] = v0;
    }
    #pragma unroll
    for (int r = 0; r < 4; ++r) {
      const int n = q0 + rg*16 + quad*4 + r;
      if (c == 0) clh[n] = lv[r];
      #pragma unroll
      for (int dt = 0; dt < 4; ++dt)
        odp[((size_t)bh*2048 + n)*64 + dt*16 + c] = (__bf16)od[rg][dt][r];
    }
  }
}

// ---------------- Combine: o[b,n,h*64+d] = (od0+od1) / (l0+l1) ----------------
__global__ __launch_bounds__(256) void combine_kernel(const __bf16* __restrict__ odp0,
                                                      const __bf16* __restrict__ odp1,
                                                      const float* __restrict__ clp,
                                                      __bf16* __restrict__ o) {
  const int rnum = blockIdx.x * 4 + (threadIdx.x >> 6);  // global row 0..98303
  const int d = threadIdx.x & 63;
  const int bh = rnum >> 11, n = rnum & 2047;
  const int b = bh / 12, h = bh % 12;
  const size_t ridx = (size_t)rnum * 64 + d;
  const float l0 = clp[(size_t)bh*2048 + n];
  const float l1 = clp[(size_t)(48 + bh)*2048 + n];
  const float v = ((float)odp0[ridx] + (float)odp1[ridx]) * __frcp_rn(l0 + l1);
  o[((size_t)b*2048 + n)*768 + h*64 + d] = (__bf16)v;
}

extern "C" void kernel_launch(void* const* d_in, const int* in_sizes, int n_in,
                              void* d_out, int out_size, void* d_ws, size_t ws_size,
                              hipStream_t stream) {
  const float* img   = (const float*)d_in[0];
  const float* gamma = (const float*)d_in[1];
  const float* beta  = (const float*)d_in[2];
  const float* wqkv  = (const float*)d_in[3];
  const float* wout  = (const float*)d_in[4];
  const float* bout  = (const float*)d_in[5];
  float* out = (float*)d_out;

  __bf16* ws = (__bf16*)d_ws;
  size_t off = 0;
  __bf16* xn    = ws + off; off += (size_t)8192*768;   // LN out; later od1 partial
  __bf16* wqkvT = ws + off; off += (size_t)2304*768;   // w_qkv^T; later clp (f32)
  __bf16* woutT = ws + off; off += (size_t)768*768;    // w_out^T
  __bf16* qs    = ws + off; off += (size_t)48*2048*64; // Q*0.125*log2e [B,H,N,D]
  __bf16* ks    = ws + off; off += (size_t)48*2048*64; // K [B,H,N,D]; later attn out [B,N,C]
  __bf16* vts   = ws + off; off += (size_t)48*64*2048; // V^T   [B,H,D,N]
  __bf16* os    = ws + off; off += (size_t)8192*768;   // od0 partial [B,H,N,D]

  __bf16* odp0 = os;             // [48][2048][64] bf16 (6.29M elems = os size)
  __bf16* odp1 = xn;             // xn dead after gemm_qkv
  float*  clp  = (float*)wqkvT;  // [2][48][2048] f32 = 786KB < 3.5MB region, dead after qkv
  __bf16* attn_out = ks;         // ks dead after attn

  prep_kernel<<<10496, 256, 0, stream>>>(img, gamma, beta, wqkv, wout, xn, wqkvT, woutT);
  gemm_qkv_kernel<<<dim3(18, 64), 256, 0, stream>>>(xn, wqkvT, qs, ks, vts);
  attn_kernel<<<1536, 256, 0, stream>>>(qs, ks, vts, odp0, odp1, clp);
  combine_kernel<<<24576, 256, 0, stream>>>(odp0, odp1, clp, attn_out);
  gemm_out_kernel<<<dim3(6, 64), 256, 0, stream>>>(attn_out, woutT, bout, img, out);
}